// Round 10
// baseline (219.949 us; speedup 1.0000x reference)
//
#include <hip/hip_runtime.h>
#include <math.h>

#define BN 1024
#define NV 5023
#define NL 68
#define NVP 5120       // padded verts (mult of 128)
#define NPL 15360      // 3*NVP rows per k-group of packed G
#define OSTR 15273     // (V+L)*3
#define KTOT 192
#define NG 24          // 192/8 k-groups

typedef unsigned short u16;
typedef short bf16x8 __attribute__((ext_vector_type(8)));
typedef u16 u16x8 __attribute__((ext_vector_type(8)));
typedef float f32x4 __attribute__((ext_vector_type(4)));

// ---------------- workspace layout (floats), 12.98 MB total ----------------
#define O_JSX  0          // jsx[15][152]
#define O_PART 4096       // part[80][15][160] (dead after k1b)
#define O_EP   4096       // E packed u16 [24][1024][16] (196608 floats) — overlays part
#define O_AREL 200704     // arel[1024][60]
#define O_WT   262144     // wT[5][NVP]              (25600)
#define O_GP   294912     // G packed u16 [24][NPL][16] (2949120 floats) -> ends 3244032

__device__ __forceinline__ u16 f2bf(float x) {
  unsigned u = __float_as_uint(x);
  return (u16)((u + 0x7FFFu + ((u >> 16) & 1u)) >> 16);
}
__device__ __forceinline__ float bf2f(u16 h) {
  return __uint_as_float(((unsigned)h) << 16);
}

// ============ K0: pack basis G -> bf16 hi/lo packed (k-major, [g][c*NVP+v][16]) + J partials + wT ====
__global__ __launch_bounds__(256) void k0(const float* __restrict__ sd,
                                          const float* __restrict__ pd,
                                          const float* __restrict__ vt,
                                          const float* __restrict__ jreg,
                                          const float* __restrict__ w,
                                          float* __restrict__ part,
                                          float* __restrict__ wT,
                                          u16* __restrict__ gp) {
  __shared__ float ldsT[64 * 208];
  __shared__ float jr[320];
  const int tid = threadIdx.x;
  const int v0 = blockIdx.x * 64;
  const int c = blockIdx.y;
  // phase 1: stage [64 v][192 k] for this c-plane
  for (int idx = tid; idx < 64 * 150; idx += 256) {
    int vv = idx / 150, k = idx - vv * 150;
    int v = v0 + vv;
    ldsT[vv * 208 + k] = (v < NV) ? sd[((size_t)v * 3 + c) * 150 + k] : 0.f;
  }
  for (int idx = tid; idx < 36 * 64; idx += 256) {
    int kk = idx >> 6, vv = idx & 63;
    int v = v0 + vv;
    ldsT[vv * 208 + 150 + kk] = (v < NV) ? pd[(size_t)kk * 15069 + (size_t)v * 3 + c] : 0.f;
  }
  for (int idx = tid; idx < 64 * 6; idx += 256) {
    int vv = idx / 6, kk = idx - vv * 6;  // k = 186..191
    int v = v0 + vv;
    ldsT[vv * 208 + 186 + kk] = (kk == 0 && v < NV) ? vt[(size_t)v * 3 + c] : 0.f;
  }
  for (int idx = tid; idx < 320; idx += 256) {
    int j = idx >> 6, vv = idx & 63;
    int v = v0 + vv;
    jr[idx] = (v < NV) ? jreg[(size_t)j * NV + v] : 0.f;
  }
  // wT (c == 0 only)
  if (c == 0) {
    for (int idx = tid; idx < 320; idx += 256) {
      int vv = idx / 5, j = idx - vv * 5;
      int v = v0 + vv;
      wT[(size_t)j * NVP + v] = (v < NV) ? w[(size_t)v * 5 + j] : 0.f;
    }
  }
  __syncthreads();
  // phase 2a: J partials over [sd|vt] columns
  if (tid < 192) {
    int k = tid;
    float s0 = 0.f, s1 = 0.f, s2 = 0.f, s3 = 0.f, s4 = 0.f;
    for (int vv = 0; vv < 64; ++vv) {
      float x = ldsT[vv * 208 + k];
      s0 = fmaf(jr[vv], x, s0);
      s1 = fmaf(jr[64 + vv], x, s1);
      s2 = fmaf(jr[128 + vv], x, s2);
      s3 = fmaf(jr[192 + vv], x, s3);
      s4 = fmaf(jr[256 + vv], x, s4);
    }
    int km = (k < 150) ? k : ((k == 186) ? 150 : -1);
    if (km >= 0) {
      size_t base = ((size_t)blockIdx.x * 15 + c) * 160;
      part[base + 0 * 480 + km] = s0;   // (vch*15 + j*3 + c)*160
      part[base + 1 * 480 + km] = s1;
      part[base + 2 * 480 + km] = s2;
      part[base + 3 * 480 + km] = s3;
      part[base + 4 * 480 + km] = s4;
    }
  }
  // phase 2b: pack to bf16 hi/lo (interleaved: [0..7]=hi, [8..15]=lo)
  {
    int q = tid >> 6, vv = tid & 63;
    int v = v0 + vv;
#pragma unroll
    for (int gg = 0; gg < 6; ++gg) {
      int g = q * 6 + gg;
      u16x8 h8, l8;
#pragma unroll
      for (int j = 0; j < 8; ++j) {
        float x = ldsT[vv * 208 + g * 8 + j];
        u16 h = f2bf(x);
        h8[j] = h;
        l8[j] = f2bf(x - bf2f(h));
      }
      size_t off = ((size_t)g * NPL + (size_t)c * NVP + v) * 16;
      *(u16x8*)(gp + off) = h8;
      *(u16x8*)(gp + off + 8) = l8;
    }
  }
}

// ============ K1b: reduce J partials -> jsx[15][152] ============
__global__ void k1b(const float* __restrict__ part, float* __restrict__ jsx) {
  int jc = blockIdx.x, k = threadIdx.x;
  if (k < 151) {
    float s = 0.f;
    for (int vch = 0; vch < 80; ++vch)
      s += part[((size_t)vch * 15 + jc) * 160 + k];
    jsx[jc * 152 + k] = s;
  }
}

// ============ K2: per-batch J, Rodrigues, chain, A_rel, packed E hi/lo ============
__global__ __launch_bounds__(64) void k2(const float* __restrict__ shp,
                                         const float* __restrict__ expr,
                                         const float* __restrict__ pose,
                                         const float* __restrict__ eye,
                                         const float* __restrict__ jsx,
                                         u16* __restrict__ ep,
                                         float* __restrict__ arel) {
  int b = blockIdx.x, t = threadIdx.x;
  __shared__ float bet[150];
  __shared__ float Rm[5][9];
  __shared__ float Tl[5][16];
  __shared__ float Am[5][16];
  __shared__ float Jl[15];
  for (int i = t; i < 150; i += 64)
    bet[i] = (i < 100) ? shp[b * 100 + i] : expr[b * 50 + (i - 100)];
  __syncthreads();
  if (t < 60) {
    int jc = t >> 2, sub = t & 3;
    float acc = 0.f;
    for (int m = 0; m < 38; ++m) {
      int l = sub + 4 * m;
      if (l < 150) acc += jsx[jc * 152 + l] * bet[l];
      else if (l == 150) acc += jsx[jc * 152 + 150];
    }
    acc += __shfl_xor(acc, 1);
    acc += __shfl_xor(acc, 2);
    if (sub == 0) Jl[jc] = acc;
  }
  __syncthreads();
  if (t < 5) {
    float r0, r1, r2;
    if (t == 0)      { r0 = pose[b*6+0]; r1 = pose[b*6+1]; r2 = pose[b*6+2]; }
    else if (t == 2) { r0 = pose[b*6+3]; r1 = pose[b*6+4]; r2 = pose[b*6+5]; }
    else if (t == 3) { r0 = eye[b*6+0];  r1 = eye[b*6+1];  r2 = eye[b*6+2];  }
    else if (t == 4) { r0 = eye[b*6+3];  r1 = eye[b*6+4];  r2 = eye[b*6+5];  }
    else             { r0 = 0.f; r1 = 0.f; r2 = 0.f; }
    float ang = sqrtf(r0*r0 + r1*r1 + r2*r2 + 1e-16f);
    float ax = r0/ang, ay = r1/ang, az = r2/ang;
    float s = sinf(ang), cc = cosf(ang), o = 1.f - cc;
    float R0 = 1.f - o*(ay*ay+az*az);
    float R1 = -s*az + o*ax*ay;
    float R2 =  s*ay + o*ax*az;
    float R3 =  s*az + o*ax*ay;
    float R4 = 1.f - o*(ax*ax+az*az);
    float R5 = -s*ax + o*ay*az;
    float R6 = -s*ay + o*ax*az;
    float R7 =  s*ax + o*ay*az;
    float R8 = 1.f - o*(ax*ax+ay*ay);
    Rm[t][0]=R0; Rm[t][1]=R1; Rm[t][2]=R2; Rm[t][3]=R3; Rm[t][4]=R4;
    Rm[t][5]=R5; Rm[t][6]=R6; Rm[t][7]=R7; Rm[t][8]=R8;
    int par = (t == 0) ? -1 : ((t == 1) ? 0 : 1);
    float j0 = Jl[t*3+0], j1 = Jl[t*3+1], j2 = Jl[t*3+2];
    if (par >= 0) { j0 -= Jl[par*3+0]; j1 -= Jl[par*3+1]; j2 -= Jl[par*3+2]; }
    Tl[t][0]=R0; Tl[t][1]=R1; Tl[t][2]=R2;  Tl[t][3]=j0;
    Tl[t][4]=R3; Tl[t][5]=R4; Tl[t][6]=R5;  Tl[t][7]=j1;
    Tl[t][8]=R6; Tl[t][9]=R7; Tl[t][10]=R8; Tl[t][11]=j2;
    Tl[t][12]=0.f; Tl[t][13]=0.f; Tl[t][14]=0.f; Tl[t][15]=1.f;
  }
  __syncthreads();
  if (t < 16) Am[0][t] = Tl[0][t];
  __syncthreads();
  if (t < 16) {
    int m = t / 4, n = t % 4;
    float s = 0.f;
#pragma unroll
    for (int k = 0; k < 4; ++k) s += Am[0][m*4+k] * Tl[1][k*4+n];
    Am[1][t] = s;
  }
  __syncthreads();
  if (t < 48) {
    int jj = 2 + t / 16, tt = t % 16;
    int m = tt / 4, n = tt % 4;
    float s = 0.f;
#pragma unroll
    for (int k = 0; k < 4; ++k) s += Am[1][m*4+k] * Tl[jj][k*4+n];
    Am[jj][tt] = s;
  }
  __syncthreads();
  if (t < 60) {
    int j = t / 12, rr = (t % 12) / 4, cc = t % 4;
    float val = Am[j][rr*4+cc];
    if (cc == 3)
      val = Am[j][rr*4+3] - (Am[j][rr*4+0]*Jl[j*3+0] + Am[j][rr*4+1]*Jl[j*3+1] + Am[j][rr*4+2]*Jl[j*3+2]);
    arel[b * 60 + t] = val;
  }
  for (int k = t; k < 192; k += 64) {
    float val;
    if (k < 150) val = bet[k];
    else if (k < 186) {
      int kk = k - 150;
      int j = kk / 9 + 1, rc = kk % 9;
      val = Rm[j][rc] - ((rc == 0 || rc == 4 || rc == 8) ? 1.f : 0.f);
    } else if (k == 186) val = 1.f;
    else val = 0.f;
    u16 h = f2bf(val);
    u16 lo = f2bf(val - bf2f(h));
    int g = k >> 3, j8 = k & 7;
    size_t eoff = ((size_t)g * 1024 + b) * 16;
    ep[eoff + j8] = h;
    ep[eoff + 8 + j8] = lo;
  }
}

// ============ K3: 4-term split-bf16 MFMA GEMM (M=batches, N=verts), XCD-swizzled, NT stores ====
// Lane owns col = vert (l15), rows = 4 batches (g0*4+r). Stores are the
// R8-proven vert-contiguous pattern but NON-TEMPORAL so the 62.5 MB write
// stream does not evict G/E from L2. A_rel broadcast from global. No LDS.
__global__ __launch_bounds__(256, 4) void k3(const u16* __restrict__ ep,
                                             const u16* __restrict__ gp,
                                             const float* __restrict__ arel,
                                             const float* __restrict__ wT,
                                             const float* __restrict__ tr,
                                             float* __restrict__ outp) {
  const int bid = blockIdx.x;          // 0..1279
  const int xcd = bid & 7, t8 = bid >> 3;      // t8: 0..159
  const int bx = xcd * 10 + (t8 % 10);         // G-slice (0..79)
  const int by = t8 / 10;                      // batch block (0..15)
  const int tid = threadIdx.x;
  const int lane = tid & 63, wb = tid >> 6;
  const int l15 = lane & 15, g0 = lane >> 4;
  const int vbase = bx * 64;
  const int brow0 = by * 64 + wb * 16;

  f32x4 accb[4][3], accs[4][3];            // [vert tile mt][plane c]
#pragma unroll
  for (int mt = 0; mt < 4; ++mt)
#pragma unroll
    for (int c = 0; c < 3; ++c)
#pragma unroll
      for (int r = 0; r < 4; ++r) { accb[mt][c][r] = 0.f; accs[mt][c][r] = 0.f; }

  size_t aoff = ((size_t)g0 * 1024 + (size_t)(brow0 + l15)) * 16;   // E (batches)
  size_t boff = ((size_t)g0 * NPL + (size_t)(vbase + l15)) * 16;    // G (verts)

  for (int ks = 0; ks < 6; ++ks) {
    bf16x8 ah = *(const bf16x8*)(ep + aoff);
    bf16x8 al = *(const bf16x8*)(ep + aoff + 8);
#pragma unroll
    for (int c = 0; c < 3; ++c) {
      bf16x8 bh[4], bl[4];
#pragma unroll
      for (int mt = 0; mt < 4; ++mt) {
        size_t o = boff + (size_t)c * (NVP * 16) + mt * 256;
        bh[mt] = *(const bf16x8*)(gp + o);
        bl[mt] = *(const bf16x8*)(gp + o + 8);
      }
#pragma unroll
      for (int mt = 0; mt < 4; ++mt) {
        accb[mt][c] = __builtin_amdgcn_mfma_f32_16x16x32_bf16(ah, bh[mt], accb[mt][c], 0, 0, 0);
        accs[mt][c] = __builtin_amdgcn_mfma_f32_16x16x32_bf16(ah, bl[mt], accs[mt][c], 0, 0, 0);
        accs[mt][c] = __builtin_amdgcn_mfma_f32_16x16x32_bf16(al, bh[mt], accs[mt][c], 0, 0, 0);
        accs[mt][c] = __builtin_amdgcn_mfma_f32_16x16x32_bf16(al, bl[mt], accs[mt][c], 0, 0, 0);
      }
    }
    aoff += (size_t)1024 * 64;
    boff += (size_t)NPL * 64;
  }

  // ---- epilogue: weights for this lane's 4 verts ----
  float wv[4][5];
#pragma unroll
  for (int mt = 0; mt < 4; ++mt)
#pragma unroll
    for (int j = 0; j < 5; ++j)
      wv[mt][j] = wT[(size_t)j * NVP + (vbase + mt * 16 + l15)];

#pragma unroll
  for (int r = 0; r < 4; ++r) {
    const int b = brow0 + g0 * 4 + r;      // this reg-row's batch
    const float t0 = tr[(size_t)b * 3 + 0];
    const float t1 = tr[(size_t)b * 3 + 1];
    const float t2 = tr[(size_t)b * 3 + 2];
    const float4* ar4 = (const float4*)(arel + (size_t)b * 60);
#pragma unroll
    for (int mt = 0; mt < 4; ++mt) {
      const float px = accb[mt][0][r] + accs[mt][0][r];
      const float py = accb[mt][1][r] + accs[mt][1][r];
      const float pz = accb[mt][2][r] + accs[mt][2][r];
      float o0 = t0, o1 = t1, o2 = t2;
#pragma unroll
      for (int j = 0; j < 5; ++j) {
        float4 a0 = ar4[j * 3 + 0];
        float4 a1 = ar4[j * 3 + 1];
        float4 a2 = ar4[j * 3 + 2];
        float yx = fmaf(a0.x, px, fmaf(a0.y, py, fmaf(a0.z, pz, a0.w)));
        float yy = fmaf(a1.x, px, fmaf(a1.y, py, fmaf(a1.z, pz, a1.w)));
        float yz = fmaf(a2.x, px, fmaf(a2.y, py, fmaf(a2.z, pz, a2.w)));
        float wj = wv[mt][j];
        o0 = fmaf(wj, yx, o0);
        o1 = fmaf(wj, yy, o1);
        o2 = fmaf(wj, yz, o2);
      }
      const int v = vbase + mt * 16 + l15;
      if (v < NV) {
        float* op = outp + (size_t)b * OSTR + (size_t)v * 3;
        __builtin_nontemporal_store(o0, op + 0);
        __builtin_nontemporal_store(o1, op + 1);
        __builtin_nontemporal_store(o2, op + 2);
      }
    }
  }
}

// ============ K4: landmarks ============
__global__ void k4(const int* __restrict__ faces, const int* __restrict__ lfi,
                   const float* __restrict__ bary, float* __restrict__ outp) {
  int idx = blockIdx.x * 256 + threadIdx.x;
  if (idx >= BN * NL * 3) return;
  int b = idx / (NL * 3), rem = idx % (NL * 3);
  int l = rem / 3, i = rem % 3;
  int fi = lfi[l];
  float s = 0.f;
#pragma unroll
  for (int f = 0; f < 3; ++f) {
    int vid = faces[fi * 3 + f];
    s += bary[l * 3 + f] * outp[(size_t)b * OSTR + (size_t)vid * 3 + i];
  }
  outp[(size_t)b * OSTR + (size_t)(NV + l) * 3 + i] = s;
}

extern "C" void kernel_launch(void* const* d_in, const int* in_sizes, int n_in,
                              void* d_out, int out_size, void* d_ws, size_t ws_size,
                              hipStream_t stream) {
  const float* shp  = (const float*)d_in[0];
  const float* expr = (const float*)d_in[1];
  const float* pose = (const float*)d_in[2];
  const float* eye  = (const float*)d_in[3];
  const float* tr   = (const float*)d_in[4];
  const float* vt   = (const float*)d_in[5];
  const float* sd   = (const float*)d_in[6];
  const float* pd   = (const float*)d_in[7];
  const float* jreg = (const float*)d_in[8];
  const float* w    = (const float*)d_in[9];
  const int* faces  = (const int*)d_in[10];
  const int* lfi    = (const int*)d_in[11];
  const float* bary = (const float*)d_in[12];
  float* ws = (float*)d_ws;
  float* jsx  = ws + O_JSX;
  float* part = ws + O_PART;
  float* arel = ws + O_AREL;
  float* wT   = ws + O_WT;
  u16* ep = (u16*)(ws + O_EP);
  u16* gp = (u16*)(ws + O_GP);
  float* outp = (float*)d_out;

  k0<<<dim3(80, 3), 256, 0, stream>>>(sd, pd, vt, jreg, w, part, wT, gp);
  k1b<<<15, 160, 0, stream>>>(part, jsx);
  k2<<<1024, 64, 0, stream>>>(shp, expr, pose, eye, jsx, ep, arel);
  k3<<<1280, 256, 0, stream>>>(ep, gp, arel, wT, tr, outp);
  k4<<<816, 256, 0, stream>>>(faces, lfi, bary, outp);
}

// Round 11
// 132.123 us; speedup vs baseline: 1.6647x; 1.6647x over previous
//
#include <hip/hip_runtime.h>
#include <math.h>

#define BN 1024
#define NV 5023
#define NL 68
#define NVP 5120       // padded verts (mult of 128)
#define NPL 15360      // 3*NVP rows per k-group of packed G
#define OSTR 15273     // (V+L)*3
#define KTOT 192
#define NG 24          // 192/8 k-groups

typedef unsigned short u16;
typedef short bf16x8 __attribute__((ext_vector_type(8)));
typedef u16 u16x8 __attribute__((ext_vector_type(8)));
typedef float f32x4 __attribute__((ext_vector_type(4)));

// ---------------- workspace layout (floats), 12.98 MB total ----------------
#define O_JSX  0          // jsx[15][152]
#define O_PART 4096       // part[80][15][160] (dead after k1b)
#define O_EP   4096       // E packed u16 [24][1024][16] (196608 floats) — overlays part
#define O_AREL 200704     // arel[1024][60]
#define O_WT   262144     // wT[5][NVP]              (25600)
#define O_GP   294912     // G packed u16 [24][NPL][16] (2949120 floats) -> ends 3244032

__device__ __forceinline__ u16 f2bf(float x) {
  unsigned u = __float_as_uint(x);
  return (u16)((u + 0x7FFFu + ((u >> 16) & 1u)) >> 16);
}
__device__ __forceinline__ float bf2f(u16 h) {
  return __uint_as_float(((unsigned)h) << 16);
}

// ============ K0: pack basis G -> bf16 hi/lo packed (k-major, [g][c*NVP+v][16]) + J partials + wT ====
__global__ __launch_bounds__(256) void k0(const float* __restrict__ sd,
                                          const float* __restrict__ pd,
                                          const float* __restrict__ vt,
                                          const float* __restrict__ jreg,
                                          const float* __restrict__ w,
                                          float* __restrict__ part,
                                          float* __restrict__ wT,
                                          u16* __restrict__ gp) {
  __shared__ float ldsT[64 * 208];
  __shared__ float jr[320];
  const int tid = threadIdx.x;
  const int v0 = blockIdx.x * 64;
  const int c = blockIdx.y;
  // phase 1: stage [64 v][192 k] for this c-plane
  for (int idx = tid; idx < 64 * 150; idx += 256) {
    int vv = idx / 150, k = idx - vv * 150;
    int v = v0 + vv;
    ldsT[vv * 208 + k] = (v < NV) ? sd[((size_t)v * 3 + c) * 150 + k] : 0.f;
  }
  for (int idx = tid; idx < 36 * 64; idx += 256) {
    int kk = idx >> 6, vv = idx & 63;
    int v = v0 + vv;
    ldsT[vv * 208 + 150 + kk] = (v < NV) ? pd[(size_t)kk * 15069 + (size_t)v * 3 + c] : 0.f;
  }
  for (int idx = tid; idx < 64 * 6; idx += 256) {
    int vv = idx / 6, kk = idx - vv * 6;  // k = 186..191
    int v = v0 + vv;
    ldsT[vv * 208 + 186 + kk] = (kk == 0 && v < NV) ? vt[(size_t)v * 3 + c] : 0.f;
  }
  for (int idx = tid; idx < 320; idx += 256) {
    int j = idx >> 6, vv = idx & 63;
    int v = v0 + vv;
    jr[idx] = (v < NV) ? jreg[(size_t)j * NV + v] : 0.f;
  }
  // wT (c == 0 only)
  if (c == 0) {
    for (int idx = tid; idx < 320; idx += 256) {
      int vv = idx / 5, j = idx - vv * 5;
      int v = v0 + vv;
      wT[(size_t)j * NVP + v] = (v < NV) ? w[(size_t)v * 5 + j] : 0.f;
    }
  }
  __syncthreads();
  // phase 2a: J partials over [sd|vt] columns
  if (tid < 192) {
    int k = tid;
    float s0 = 0.f, s1 = 0.f, s2 = 0.f, s3 = 0.f, s4 = 0.f;
    for (int vv = 0; vv < 64; ++vv) {
      float x = ldsT[vv * 208 + k];
      s0 = fmaf(jr[vv], x, s0);
      s1 = fmaf(jr[64 + vv], x, s1);
      s2 = fmaf(jr[128 + vv], x, s2);
      s3 = fmaf(jr[192 + vv], x, s3);
      s4 = fmaf(jr[256 + vv], x, s4);
    }
    int km = (k < 150) ? k : ((k == 186) ? 150 : -1);
    if (km >= 0) {
      size_t base = ((size_t)blockIdx.x * 15 + c) * 160;
      part[base + 0 * 480 + km] = s0;   // (vch*15 + j*3 + c)*160
      part[base + 1 * 480 + km] = s1;
      part[base + 2 * 480 + km] = s2;
      part[base + 3 * 480 + km] = s3;
      part[base + 4 * 480 + km] = s4;
    }
  }
  // phase 2b: pack to bf16 hi/lo (interleaved: [0..7]=hi, [8..15]=lo)
  {
    int q = tid >> 6, vv = tid & 63;
    int v = v0 + vv;
#pragma unroll
    for (int gg = 0; gg < 6; ++gg) {
      int g = q * 6 + gg;
      u16x8 h8, l8;
#pragma unroll
      for (int j = 0; j < 8; ++j) {
        float x = ldsT[vv * 208 + g * 8 + j];
        u16 h = f2bf(x);
        h8[j] = h;
        l8[j] = f2bf(x - bf2f(h));
      }
      size_t off = ((size_t)g * NPL + (size_t)c * NVP + v) * 16;
      *(u16x8*)(gp + off) = h8;
      *(u16x8*)(gp + off + 8) = l8;
    }
  }
}

// ============ K1b: reduce J partials -> jsx[15][152] ============
__global__ void k1b(const float* __restrict__ part, float* __restrict__ jsx) {
  int jc = blockIdx.x, k = threadIdx.x;
  if (k < 151) {
    float s = 0.f;
    for (int vch = 0; vch < 80; ++vch)
      s += part[((size_t)vch * 15 + jc) * 160 + k];
    jsx[jc * 152 + k] = s;
  }
}

// ============ K2: per-batch J, Rodrigues, chain, A_rel, packed E hi/lo ============
__global__ __launch_bounds__(64) void k2(const float* __restrict__ shp,
                                         const float* __restrict__ expr,
                                         const float* __restrict__ pose,
                                         const float* __restrict__ eye,
                                         const float* __restrict__ jsx,
                                         u16* __restrict__ ep,
                                         float* __restrict__ arel) {
  int b = blockIdx.x, t = threadIdx.x;
  __shared__ float bet[150];
  __shared__ float Rm[5][9];
  __shared__ float Tl[5][16];
  __shared__ float Am[5][16];
  __shared__ float Jl[15];
  for (int i = t; i < 150; i += 64)
    bet[i] = (i < 100) ? shp[b * 100 + i] : expr[b * 50 + (i - 100)];
  __syncthreads();
  if (t < 60) {
    int jc = t >> 2, sub = t & 3;
    float acc = 0.f;
    for (int m = 0; m < 38; ++m) {
      int l = sub + 4 * m;
      if (l < 150) acc += jsx[jc * 152 + l] * bet[l];
      else if (l == 150) acc += jsx[jc * 152 + 150];
    }
    acc += __shfl_xor(acc, 1);
    acc += __shfl_xor(acc, 2);
    if (sub == 0) Jl[jc] = acc;
  }
  __syncthreads();
  if (t < 5) {
    float r0, r1, r2;
    if (t == 0)      { r0 = pose[b*6+0]; r1 = pose[b*6+1]; r2 = pose[b*6+2]; }
    else if (t == 2) { r0 = pose[b*6+3]; r1 = pose[b*6+4]; r2 = pose[b*6+5]; }
    else if (t == 3) { r0 = eye[b*6+0];  r1 = eye[b*6+1];  r2 = eye[b*6+2];  }
    else if (t == 4) { r0 = eye[b*6+3];  r1 = eye[b*6+4];  r2 = eye[b*6+5];  }
    else             { r0 = 0.f; r1 = 0.f; r2 = 0.f; }
    float ang = sqrtf(r0*r0 + r1*r1 + r2*r2 + 1e-16f);
    float ax = r0/ang, ay = r1/ang, az = r2/ang;
    float s = sinf(ang), cc = cosf(ang), o = 1.f - cc;
    float R0 = 1.f - o*(ay*ay+az*az);
    float R1 = -s*az + o*ax*ay;
    float R2 =  s*ay + o*ax*az;
    float R3 =  s*az + o*ax*ay;
    float R4 = 1.f - o*(ax*ax+az*az);
    float R5 = -s*ax + o*ay*az;
    float R6 = -s*ay + o*ax*az;
    float R7 =  s*ax + o*ay*az;
    float R8 = 1.f - o*(ax*ax+ay*ay);
    Rm[t][0]=R0; Rm[t][1]=R1; Rm[t][2]=R2; Rm[t][3]=R3; Rm[t][4]=R4;
    Rm[t][5]=R5; Rm[t][6]=R6; Rm[t][7]=R7; Rm[t][8]=R8;
    int par = (t == 0) ? -1 : ((t == 1) ? 0 : 1);
    float j0 = Jl[t*3+0], j1 = Jl[t*3+1], j2 = Jl[t*3+2];
    if (par >= 0) { j0 -= Jl[par*3+0]; j1 -= Jl[par*3+1]; j2 -= Jl[par*3+2]; }
    Tl[t][0]=R0; Tl[t][1]=R1; Tl[t][2]=R2;  Tl[t][3]=j0;
    Tl[t][4]=R3; Tl[t][5]=R4; Tl[t][6]=R5;  Tl[t][7]=j1;
    Tl[t][8]=R6; Tl[t][9]=R7; Tl[t][10]=R8; Tl[t][11]=j2;
    Tl[t][12]=0.f; Tl[t][13]=0.f; Tl[t][14]=0.f; Tl[t][15]=1.f;
  }
  __syncthreads();
  if (t < 16) Am[0][t] = Tl[0][t];
  __syncthreads();
  if (t < 16) {
    int m = t / 4, n = t % 4;
    float s = 0.f;
#pragma unroll
    for (int k = 0; k < 4; ++k) s += Am[0][m*4+k] * Tl[1][k*4+n];
    Am[1][t] = s;
  }
  __syncthreads();
  if (t < 48) {
    int jj = 2 + t / 16, tt = t % 16;
    int m = tt / 4, n = tt % 4;
    float s = 0.f;
#pragma unroll
    for (int k = 0; k < 4; ++k) s += Am[1][m*4+k] * Tl[jj][k*4+n];
    Am[jj][tt] = s;
  }
  __syncthreads();
  if (t < 60) {
    int j = t / 12, rr = (t % 12) / 4, cc = t % 4;
    float val = Am[j][rr*4+cc];
    if (cc == 3)
      val = Am[j][rr*4+3] - (Am[j][rr*4+0]*Jl[j*3+0] + Am[j][rr*4+1]*Jl[j*3+1] + Am[j][rr*4+2]*Jl[j*3+2]);
    arel[b * 60 + t] = val;
  }
  for (int k = t; k < 192; k += 64) {
    float val;
    if (k < 150) val = bet[k];
    else if (k < 186) {
      int kk = k - 150;
      int j = kk / 9 + 1, rc = kk % 9;
      val = Rm[j][rc] - ((rc == 0 || rc == 4 || rc == 8) ? 1.f : 0.f);
    } else if (k == 186) val = 1.f;
    else val = 0.f;
    u16 h = f2bf(val);
    u16 lo = f2bf(val - bf2f(h));
    int g = k >> 3, j8 = k & 7;
    size_t eoff = ((size_t)g * 1024 + b) * 16;
    ep[eoff + j8] = h;
    ep[eoff + 8 + j8] = lo;
  }
}

// ============ K3: G-in-LDS MFMA GEMM. Block = 16 verts x 512 batches. ============
// G-slice (36.9 KB) staged to LDS once -> G fetched from HBM exactly once per
// block (2x total). Per ks each wave holds its 6 G fragments in registers and
// reuses them across 8 batch-tiles. No barriers in the k-loop. Epilogue and
// store pattern identical math to R8 (proven correct).
__global__ __launch_bounds__(256, 2) void k3(const u16* __restrict__ ep,
                                             const u16* __restrict__ gp,
                                             const float* __restrict__ arel,
                                             const float* __restrict__ w,
                                             const float* __restrict__ tr,
                                             float* __restrict__ outp) {
  __shared__ uint4 sG[2304];   // 36864 B: [g(24)][c(3)][vloc(16)][32B hi/lo]
  const int bid = blockIdx.x;            // 0..627
  const int vb = bid >> 1, bhalf = bid & 1;
  const int vbase = vb * 16;
  const int tid = threadIdx.x;
  const int lane = tid & 63, wb = tid >> 6;
  const int l15 = lane & 15, g0 = lane >> 4;

  // ---- stage G-slice into LDS (72 chunks of 512B, each contiguous in gp) ----
  const uint4* gp4 = (const uint4*)gp;
  for (int idx = tid; idx < 2304; idx += 256) {
    int ch = idx >> 5, off = idx & 31;   // chunk = g*3+c, 32 uint4 per chunk
    int g = ch / 3, c = ch - g * 3;
    sG[idx] = gp4[((size_t)g * NPL + (size_t)c * NVP + vbase) * 2 + off];
  }
  __syncthreads();

  f32x4 accb[8][3], accs[8][3];          // [batch tile][plane c]
#pragma unroll
  for (int t = 0; t < 8; ++t)
#pragma unroll
    for (int c = 0; c < 3; ++c)
#pragma unroll
      for (int r = 0; r < 4; ++r) { accb[t][c][r] = 0.f; accs[t][c][r] = 0.f; }

  const int btile0 = bhalf * 32 + wb * 8;   // this wave's first batch-tile

  for (int ks = 0; ks < 6; ++ks) {
    const int g = ks * 4 + g0;
    // G fragments for this wave's k-slot, all 3 planes, from LDS
    bf16x8 bh[3], bl[3];
#pragma unroll
    for (int c = 0; c < 3; ++c) {
      const u16* sgp = (const u16*)sG + (((size_t)(g * 3 + c) * 16 + l15) << 4);
      bh[c] = *(const bf16x8*)sgp;
      bl[c] = *(const bf16x8*)(sgp + 8);
    }
#pragma unroll
    for (int t = 0; t < 8; ++t) {
      size_t eoff = ((size_t)g * 1024 + (size_t)(btile0 + t) * 16 + l15) * 16;
      bf16x8 ah = *(const bf16x8*)(ep + eoff);
      bf16x8 al = *(const bf16x8*)(ep + eoff + 8);
#pragma unroll
      for (int c = 0; c < 3; ++c) {
        accb[t][c] = __builtin_amdgcn_mfma_f32_16x16x32_bf16(ah, bh[c], accb[t][c], 0, 0, 0);
        accs[t][c] = __builtin_amdgcn_mfma_f32_16x16x32_bf16(ah, bl[c], accs[t][c], 0, 0, 0);
        accs[t][c] = __builtin_amdgcn_mfma_f32_16x16x32_bf16(al, bh[c], accs[t][c], 0, 0, 0);
        accs[t][c] = __builtin_amdgcn_mfma_f32_16x16x32_bf16(al, bl[c], accs[t][c], 0, 0, 0);
      }
    }
  }

  // ---- epilogue: lane's single vert, 32 batches ----
  const int v = vbase + l15;
  const int v_c = (v < NV) ? v : NV - 1;
  float wreg[5];
#pragma unroll
  for (int j = 0; j < 5; ++j) wreg[j] = w[(size_t)v_c * 5 + j];

#pragma unroll
  for (int t = 0; t < 8; ++t) {
#pragma unroll
    for (int r = 0; r < 4; ++r) {
      const int b = (btile0 + t) * 16 + g0 * 4 + r;
      const float t0 = tr[(size_t)b * 3 + 0];
      const float t1 = tr[(size_t)b * 3 + 1];
      const float t2 = tr[(size_t)b * 3 + 2];
      const float4* ar4 = (const float4*)(arel + (size_t)b * 60);
      const float px = accb[t][0][r] + accs[t][0][r];
      const float py = accb[t][1][r] + accs[t][1][r];
      const float pz = accb[t][2][r] + accs[t][2][r];
      float o0 = t0, o1 = t1, o2 = t2;
#pragma unroll
      for (int j = 0; j < 5; ++j) {
        float4 a0 = ar4[j * 3 + 0];
        float4 a1 = ar4[j * 3 + 1];
        float4 a2 = ar4[j * 3 + 2];
        float yx = fmaf(a0.x, px, fmaf(a0.y, py, fmaf(a0.z, pz, a0.w)));
        float yy = fmaf(a1.x, px, fmaf(a1.y, py, fmaf(a1.z, pz, a1.w)));
        float yz = fmaf(a2.x, px, fmaf(a2.y, py, fmaf(a2.z, pz, a2.w)));
        float wj = wreg[j];
        o0 = fmaf(wj, yx, o0);
        o1 = fmaf(wj, yy, o1);
        o2 = fmaf(wj, yz, o2);
      }
      if (v < NV) {
        float* op = outp + (size_t)b * OSTR + (size_t)v * 3;
        op[0] = o0; op[1] = o1; op[2] = o2;
      }
    }
  }
}

// ============ K4: landmarks ============
__global__ void k4(const int* __restrict__ faces, const int* __restrict__ lfi,
                   const float* __restrict__ bary, float* __restrict__ outp) {
  int idx = blockIdx.x * 256 + threadIdx.x;
  if (idx >= BN * NL * 3) return;
  int b = idx / (NL * 3), rem = idx % (NL * 3);
  int l = rem / 3, i = rem % 3;
  int fi = lfi[l];
  float s = 0.f;
#pragma unroll
  for (int f = 0; f < 3; ++f) {
    int vid = faces[fi * 3 + f];
    s += bary[l * 3 + f] * outp[(size_t)b * OSTR + (size_t)vid * 3 + i];
  }
  outp[(size_t)b * OSTR + (size_t)(NV + l) * 3 + i] = s;
}

extern "C" void kernel_launch(void* const* d_in, const int* in_sizes, int n_in,
                              void* d_out, int out_size, void* d_ws, size_t ws_size,
                              hipStream_t stream) {
  const float* shp  = (const float*)d_in[0];
  const float* expr = (const float*)d_in[1];
  const float* pose = (const float*)d_in[2];
  const float* eye  = (const float*)d_in[3];
  const float* tr   = (const float*)d_in[4];
  const float* vt   = (const float*)d_in[5];
  const float* sd   = (const float*)d_in[6];
  const float* pd   = (const float*)d_in[7];
  const float* jreg = (const float*)d_in[8];
  const float* w    = (const float*)d_in[9];
  const int* faces  = (const int*)d_in[10];
  const int* lfi    = (const int*)d_in[11];
  const float* bary = (const float*)d_in[12];
  float* ws = (float*)d_ws;
  float* jsx  = ws + O_JSX;
  float* part = ws + O_PART;
  float* arel = ws + O_AREL;
  float* wT   = ws + O_WT;
  u16* ep = (u16*)(ws + O_EP);
  u16* gp = (u16*)(ws + O_GP);
  float* outp = (float*)d_out;

  k0<<<dim3(80, 3), 256, 0, stream>>>(sd, pd, vt, jreg, w, part, wT, gp);
  k1b<<<15, 160, 0, stream>>>(part, jsx);
  k2<<<1024, 64, 0, stream>>>(shp, expr, pose, eye, jsx, ep, arel);
  k3<<<628, 256, 0, stream>>>(ep, gp, arel, w, tr, outp);
  k4<<<816, 256, 0, stream>>>(faces, lfi, bary, outp);
}